// Round 1
// baseline (6020.347 us; speedup 1.0000x reference)
//
#include <hip/hip_runtime.h>

#define DIM 1536
#define NH 12
#define HD 128

// C[M,N] = A[M,K] @ B[N,K]^T + bias[N]   (all f32, row-major)
__global__ __launch_bounds__(256) void gemm_bias_tn(
    const float* __restrict__ A, const float* __restrict__ B,
    const float* __restrict__ bias, float* __restrict__ C,
    int M, int N, int K)
{
    __shared__ float As[64][17];
    __shared__ float Bs[64][17];
    const int tid = threadIdx.x;
    const int tx = tid & 15, ty = tid >> 4;
    const int m0 = blockIdx.y * 64, n0 = blockIdx.x * 64;
    float acc[4][4] = {};
    for (int kk = 0; kk < K; kk += 16) {
        #pragma unroll
        for (int i = 0; i < 4; ++i) {
            int e = tid + i * 256;
            int r = e >> 4, c = e & 15;
            int m = m0 + r;
            As[r][c] = (m < M) ? A[(size_t)m * K + kk + c] : 0.f;
            int nn = n0 + r;
            Bs[r][c] = (nn < N) ? B[(size_t)nn * K + kk + c] : 0.f;
        }
        __syncthreads();
        #pragma unroll
        for (int kc = 0; kc < 16; ++kc) {
            float a[4], b[4];
            #pragma unroll
            for (int i = 0; i < 4; ++i) a[i] = As[ty * 4 + i][kc];
            #pragma unroll
            for (int j = 0; j < 4; ++j) b[j] = Bs[tx * 4 + j][kc];
            #pragma unroll
            for (int i = 0; i < 4; ++i)
                #pragma unroll
                for (int j = 0; j < 4; ++j)
                    acc[i][j] += a[i] * b[j];
        }
        __syncthreads();
    }
    #pragma unroll
    for (int i = 0; i < 4; ++i) {
        int m = m0 + ty * 4 + i;
        if (m >= M) continue;
        #pragma unroll
        for (int j = 0; j < 4; ++j) {
            int nn = n0 + tx * 4 + j;
            if (nn < N) C[(size_t)m * N + nn] = acc[i][j] + bias[nn];
        }
    }
}

// In-place RMSNorm (over DIM) + weight + 3D RoPE on a (S, DIM) tensor.
__global__ __launch_bounds__(256) void rms_rope_kernel(
    float* __restrict__ x, const float* __restrict__ w,
    const float* __restrict__ freqs,
    const int* __restrict__ fp, const int* __restrict__ hp,
    const int* __restrict__ wp, const int* __restrict__ gip)
{
    const int s = blockIdx.x;
    const int tid = threadIdx.x;
    float* row = x + (size_t)s * DIM;
    float ss = 0.f;
    for (int c = tid; c < DIM; c += 256) { float v = row[c]; ss += v * v; }
    #pragma unroll
    for (int off = 32; off > 0; off >>= 1) ss += __shfl_down(ss, off, 64);
    __shared__ float red[4];
    if ((tid & 63) == 0) red[tid >> 6] = ss;
    __syncthreads();
    const float tot = red[0] + red[1] + red[2] + red[3];
    const float scale = rsqrtf(tot / (float)DIM + 1e-6f);
    const int f = *fp, h = *hp, ww = *wp, gi = *gip;
    const int hw = h * ww;
    const int fi = s / hw;
    const int rem = s - fi * hw;
    const int hi = rem / ww;
    const int wi = rem - hi * ww;
    const int sf = gi * f;
    // c = HD/2 = 64 pairs; parts: cf=22 (frame), ch=21 (height), cw=21 (width)
    for (int p = tid; p < DIM / 2; p += 256) {
        int n = p >> 6, i = p & 63;
        int pos = (i < 22) ? (sf + fi) : (i < 43) ? hi : wi;
        float cs = freqs[pos * 128 + i * 2];
        float sn = freqs[pos * 128 + i * 2 + 1];
        int base = n * HD + 2 * i;
        float x0 = row[base] * scale * w[base];
        float x1 = row[base + 1] * scale * w[base + 1];
        row[base] = x0 * cs - x1 * sn;
        row[base + 1] = x0 * sn + x1 * cs;
    }
}

// Flash-style attention, f32. One block = (head n, 32-query tile).
// Keys j < start come from cache, j >= start from freshly computed k/v.
#define TK 48
__global__ __launch_bounds__(256) void attn_kernel(
    const float* __restrict__ q, const float* __restrict__ knew,
    const float* __restrict__ vnew, const float* __restrict__ kcache,
    const float* __restrict__ vcache, float* __restrict__ o,
    int S, const int* __restrict__ gip)
{
    const int n = blockIdx.x;
    const int qt = blockIdx.y;
    const int tid = threadIdx.x;
    const int r = tid >> 3;          // query row within tile (0..31)
    const int dg = tid & 7;          // dim group: 16 consecutive dims
    const int qrow = qt * 32 + r;
    const bool qvalid = qrow < S;
    const int start = (*gip) * S;
    const int nk = start + S;
    float qreg[16];
    if (qvalid) {
        const float* qp = q + (size_t)qrow * DIM + n * HD + dg * 16;
        #pragma unroll
        for (int j = 0; j < 16; ++j) qreg[j] = qp[j];
    } else {
        #pragma unroll
        for (int j = 0; j < 16; ++j) qreg[j] = 0.f;
    }
    __shared__ float Ks[TK][HD];
    __shared__ float Vs[TK][HD];
    float m = -1e30f, l = 0.f;
    float acc[16] = {};
    const float sc = 0.08838834764831845f;   // 1/sqrt(128)
    for (int k0 = 0; k0 < nk; k0 += TK) {
        const int kcnt = min(TK, nk - k0);
        for (int e = tid; e < TK * 32; e += 256) {   // float4 granules
            int kr = e >> 5, c4 = e & 31;
            if (kr < kcnt) {
                int kj = k0 + kr;
                const float* kbase = (kj < start) ? (kcache + (size_t)kj * DIM + n * HD)
                                                  : (knew + (size_t)(kj - start) * DIM + n * HD);
                const float* vbase = (kj < start) ? (vcache + (size_t)kj * DIM + n * HD)
                                                  : (vnew + (size_t)(kj - start) * DIM + n * HD);
                ((float4*)Ks[kr])[c4] = ((const float4*)kbase)[c4];
                ((float4*)Vs[kr])[c4] = ((const float4*)vbase)[c4];
            }
        }
        __syncthreads();
        for (int k = 0; k < kcnt; ++k) {
            const float4* k4 = (const float4*)&Ks[k][dg * 16];
            float part = 0.f;
            #pragma unroll
            for (int j4 = 0; j4 < 4; ++j4) {
                float4 kv = k4[j4];
                part += qreg[j4*4+0]*kv.x + qreg[j4*4+1]*kv.y
                      + qreg[j4*4+2]*kv.z + qreg[j4*4+3]*kv.w;
            }
            // reduce partial dots across the 8 dim-groups (contiguous lanes)
            part += __shfl_xor(part, 1);
            part += __shfl_xor(part, 2);
            part += __shfl_xor(part, 4);
            float s_ = part * sc;
            float mn = fmaxf(m, s_);
            float alpha = __expf(m - mn);
            float p = __expf(s_ - mn);
            l = l * alpha + p;
            m = mn;
            const float4* v4 = (const float4*)&Vs[k][dg * 16];
            #pragma unroll
            for (int j4 = 0; j4 < 4; ++j4) {
                float4 vv = v4[j4];
                acc[j4*4+0] = acc[j4*4+0]*alpha + p*vv.x;
                acc[j4*4+1] = acc[j4*4+1]*alpha + p*vv.y;
                acc[j4*4+2] = acc[j4*4+2]*alpha + p*vv.z;
                acc[j4*4+3] = acc[j4*4+3]*alpha + p*vv.w;
            }
        }
        __syncthreads();
    }
    if (qvalid) {
        float inv = 1.f / l;
        float* op = o + (size_t)qrow * DIM + n * HD + dg * 16;
        #pragma unroll
        for (int j = 0; j < 16; ++j) op[j] = acc[j] * inv;
    }
}

extern "C" void kernel_launch(void* const* d_in, const int* in_sizes, int n_in,
                              void* d_out, int out_size, void* d_ws, size_t ws_size,
                              hipStream_t stream)
{
    const float* x      = (const float*)d_in[0];
    const float* wq     = (const float*)d_in[1];
    const float* bq     = (const float*)d_in[2];
    const float* wk     = (const float*)d_in[3];
    const float* bk     = (const float*)d_in[4];
    const float* wv     = (const float*)d_in[5];
    const float* bv     = (const float*)d_in[6];
    const float* wo     = (const float*)d_in[7];
    const float* bo     = (const float*)d_in[8];
    const float* nqw    = (const float*)d_in[9];
    const float* nkw    = (const float*)d_in[10];
    const float* freqs  = (const float*)d_in[11];
    const float* kcache = (const float*)d_in[12];
    const float* vcache = (const float*)d_in[13];
    const int*   fp     = (const int*)d_in[14];
    const int*   hp     = (const int*)d_in[15];
    const int*   wp     = (const int*)d_in[16];
    const int*   gip    = (const int*)d_in[17];

    const int S = in_sizes[0] / DIM;

    float* q = (float*)d_ws;                 // S*DIM
    float* k = q + (size_t)S * DIM;          // S*DIM
    float* v = k + (size_t)S * DIM;          // S*DIM
    float* o = v + (size_t)S * DIM;          // S*DIM
    float* out = (float*)d_out;

    dim3 blk(256);
    dim3 ggrid(DIM / 64, (S + 63) / 64);
    gemm_bias_tn<<<ggrid, blk, 0, stream>>>(x, wq, bq, q, S, DIM, DIM);
    gemm_bias_tn<<<ggrid, blk, 0, stream>>>(x, wk, bk, k, S, DIM, DIM);
    gemm_bias_tn<<<ggrid, blk, 0, stream>>>(x, wv, bv, v, S, DIM, DIM);
    rms_rope_kernel<<<dim3(S), blk, 0, stream>>>(q, nqw, freqs, fp, hp, wp, gip);
    rms_rope_kernel<<<dim3(S), blk, 0, stream>>>(k, nkw, freqs, fp, hp, wp, gip);
    attn_kernel<<<dim3(NH, (S + 31) / 32), blk, 0, stream>>>(q, k, v, kcache, vcache, o, S, gip);
    gemm_bias_tn<<<ggrid, blk, 0, stream>>>(o, wo, bo, out, S, DIM, DIM);
}

// Round 3
// 2746.842 us; speedup vs baseline: 2.1917x; 2.1917x over previous
//
#include <hip/hip_runtime.h>

#define DIM 1536
#define NH 12
#define HD 128

typedef _Float16 half2_t __attribute__((ext_vector_type(2)));
typedef _Float16 half8_t __attribute__((ext_vector_type(8)));
typedef float f32x4 __attribute__((ext_vector_type(4)));

__device__ __forceinline__ half2_t pkrtz(float a, float b) {
    return __builtin_bit_cast(half2_t, __builtin_amdgcn_cvt_pkrtz(a, b));
}

// ---------------- GEMM: C[M,N] = A[M,K] @ B[N,K]^T + bias[N] (f32) ----------------
__global__ __launch_bounds__(256) void gemm_bias_tn(
    const float* __restrict__ A, const float* __restrict__ B,
    const float* __restrict__ bias, float* __restrict__ C,
    int M, int N, int K)
{
    __shared__ float As[64][17];
    __shared__ float Bs[64][17];
    const int tid = threadIdx.x;
    const int tx = tid & 15, ty = tid >> 4;
    const int m0 = blockIdx.y * 64, n0 = blockIdx.x * 64;
    float acc[4][4] = {};
    for (int kk = 0; kk < K; kk += 16) {
        #pragma unroll
        for (int i = 0; i < 4; ++i) {
            int e = tid + i * 256;
            int r = e >> 4, c = e & 15;
            int m = m0 + r;
            As[r][c] = (m < M) ? A[(size_t)m * K + kk + c] : 0.f;
            int nn = n0 + r;
            Bs[r][c] = (nn < N) ? B[(size_t)nn * K + kk + c] : 0.f;
        }
        __syncthreads();
        #pragma unroll
        for (int kc = 0; kc < 16; ++kc) {
            float a[4], b[4];
            #pragma unroll
            for (int i = 0; i < 4; ++i) a[i] = As[ty * 4 + i][kc];
            #pragma unroll
            for (int j = 0; j < 4; ++j) b[j] = Bs[tx * 4 + j][kc];
            #pragma unroll
            for (int i = 0; i < 4; ++i)
                #pragma unroll
                for (int j = 0; j < 4; ++j)
                    acc[i][j] += a[i] * b[j];
        }
        __syncthreads();
    }
    #pragma unroll
    for (int i = 0; i < 4; ++i) {
        int m = m0 + ty * 4 + i;
        if (m >= M) continue;
        #pragma unroll
        for (int j = 0; j < 4; ++j) {
            int nn = n0 + tx * 4 + j;
            if (nn < N) C[(size_t)m * N + nn] = acc[i][j] + bias[nn];
        }
    }
}

// ---------------- RMSNorm + 3D RoPE (in-place, f32) ----------------
__global__ __launch_bounds__(256) void rms_rope_kernel(
    float* __restrict__ x, const float* __restrict__ w,
    const float* __restrict__ freqs,
    const int* __restrict__ fp, const int* __restrict__ hp,
    const int* __restrict__ wp, const int* __restrict__ gip)
{
    const int s = blockIdx.x;
    const int tid = threadIdx.x;
    float* row = x + (size_t)s * DIM;
    float ss = 0.f;
    for (int c = tid; c < DIM; c += 256) { float v = row[c]; ss += v * v; }
    #pragma unroll
    for (int off = 32; off > 0; off >>= 1) ss += __shfl_down(ss, off, 64);
    __shared__ float red[4];
    if ((tid & 63) == 0) red[tid >> 6] = ss;
    __syncthreads();
    const float tot = red[0] + red[1] + red[2] + red[3];
    const float scale = rsqrtf(tot / (float)DIM + 1e-6f);
    const int f = *fp, h = *hp, ww = *wp, gi = *gip;
    const int hw = h * ww;
    const int fi = s / hw;
    const int rem = s - fi * hw;
    const int hi = rem / ww;
    const int wi = rem - hi * ww;
    const int sf = gi * f;
    for (int p = tid; p < DIM / 2; p += 256) {
        int n = p >> 6, i = p & 63;
        int pos = (i < 22) ? (sf + fi) : (i < 43) ? hi : wi;
        float cs = freqs[pos * 128 + i * 2];
        float sn = freqs[pos * 128 + i * 2 + 1];
        int base = n * HD + 2 * i;
        float x0 = row[base] * scale * w[base];
        float x1 = row[base + 1] * scale * w[base + 1];
        row[base] = x0 * cs - x1 * sn;
        row[base + 1] = x0 * sn + x1 * cs;
    }
}

// ---------------- MFMA flash attention ----------------
// block = 128 threads (2 waves); wave w handles 32 q-rows; block = 64 q-rows, one head.
// K tile = 32 keys staged to LDS as fp16 hi/lo; V staged transposed.
#define KT 32
#define KSTR 136   // K LDS row stride (halves): 68 words, == 4 mod 32
#define VSTR 40    // Vt LDS row stride (halves): 20 words
#define PSTR 36    // P LDS row stride (floats)

__global__ __launch_bounds__(128, 2) void attn_mfma(
    const float* __restrict__ q, const float* __restrict__ knew,
    const float* __restrict__ vnew, const float* __restrict__ kcache,
    const float* __restrict__ vcache, float* __restrict__ o,
    int S, const int* __restrict__ gip)
{
    __shared__ __align__(16) _Float16 Kh[KT][KSTR], Kl[KT][KSTR];
    __shared__ __align__(16) _Float16 Vth[HD][VSTR], Vtl[HD][VSTR];
    __shared__ __align__(16) float Pf[2][32][PSTR];

    const int n = blockIdx.x;          // head
    const int q0 = blockIdx.y * 64;    // q-tile base
    const int tid = threadIdx.x;
    const int wave = tid >> 6;
    const int lane = tid & 63;
    const int l16 = lane & 15;
    const int quad = lane >> 4;
    const int nHD = n * HD;
    const int start = gip[0] * S;
    const int nk = start + S;
    const float sc = 0.08838834764831845f;  // 1/sqrt(128)

    // ---- load Q fragments (register-resident, fp16 hi/lo split) ----
    half8_t qh[2][4], ql[2][4];
    #pragma unroll
    for (int qs = 0; qs < 2; ++qs) {
        const int qrow = q0 + wave * 32 + qs * 16 + l16;
        const bool qv = qrow < S;
        const float* qp = q + (size_t)(qv ? qrow : 0) * DIM + nHD + quad * 8;
        #pragma unroll
        for (int db = 0; db < 4; ++db) {
            float4 a, b;
            if (qv) {
                a = *(const float4*)(qp + db * 32);
                b = *(const float4*)(qp + db * 32 + 4);
            } else {
                a = make_float4(0, 0, 0, 0); b = make_float4(0, 0, 0, 0);
            }
            half2_t h0 = pkrtz(a.x, a.y), h1 = pkrtz(a.z, a.w);
            half2_t h2 = pkrtz(b.x, b.y), h3 = pkrtz(b.z, b.w);
            half2_t g0 = pkrtz(a.x - (float)h0.x, a.y - (float)h0.y);
            half2_t g1 = pkrtz(a.z - (float)h1.x, a.w - (float)h1.y);
            half2_t g2 = pkrtz(b.x - (float)h2.x, b.y - (float)h2.y);
            half2_t g3 = pkrtz(b.z - (float)h3.x, b.w - (float)h3.y);
            half8_t hv, lv;
            hv[0]=h0.x; hv[1]=h0.y; hv[2]=h1.x; hv[3]=h1.y;
            hv[4]=h2.x; hv[5]=h2.y; hv[6]=h3.x; hv[7]=h3.y;
            lv[0]=g0.x; lv[1]=g0.y; lv[2]=g1.x; lv[3]=g1.y;
            lv[4]=g2.x; lv[5]=g2.y; lv[6]=g3.x; lv[7]=g3.y;
            qh[qs][db] = hv; ql[qs][db] = lv;
        }
    }

    f32x4 O[2][8];
    #pragma unroll
    for (int qs = 0; qs < 2; ++qs)
        #pragma unroll
        for (int ds = 0; ds < 8; ++ds) O[qs][ds] = (f32x4){0.f, 0.f, 0.f, 0.f};
    float mrow[2][4], lrow[2][4];
    #pragma unroll
    for (int qs = 0; qs < 2; ++qs)
        #pragma unroll
        for (int r = 0; r < 4; ++r) { mrow[qs][r] = -1e30f; lrow[qs][r] = 0.f; }

    // staging coordinates
    const int skey = tid >> 2;          // 0..31  (K)
    const int sd0  = (tid & 3) * 32;    // d-chunk base (K)
    const int vkp  = tid & 15;          // key pair (V)
    const int vd0  = (tid >> 4) * 16;   // d-chunk base (V)

    for (int k0 = 0; k0 < nk; k0 += KT) {
        __syncthreads();   // protect LDS from previous iteration's readers
        // ---- stage K (fp16 hi/lo) ----
        {
            const int kj = k0 + skey;
            const float* kr = nullptr;
            if (kj < nk)
                kr = (kj < start) ? (kcache + (size_t)kj * DIM + nHD + sd0)
                                  : (knew + (size_t)(kj - start) * DIM + nHD + sd0);
            #pragma unroll
            for (int g = 0; g < 4; ++g) {
                float4 a, b;
                if (kr) {
                    a = *(const float4*)(kr + g * 8);
                    b = *(const float4*)(kr + g * 8 + 4);
                } else {
                    a = make_float4(0, 0, 0, 0); b = make_float4(0, 0, 0, 0);
                }
                half2_t h0 = pkrtz(a.x, a.y), h1 = pkrtz(a.z, a.w);
                half2_t h2 = pkrtz(b.x, b.y), h3 = pkrtz(b.z, b.w);
                half2_t g0 = pkrtz(a.x - (float)h0.x, a.y - (float)h0.y);
                half2_t g1 = pkrtz(a.z - (float)h1.x, a.w - (float)h1.y);
                half2_t g2 = pkrtz(b.x - (float)h2.x, b.y - (float)h2.y);
                half2_t g3 = pkrtz(b.z - (float)h3.x, b.w - (float)h3.y);
                half8_t hv, lv;
                hv[0]=h0.x; hv[1]=h0.y; hv[2]=h1.x; hv[3]=h1.y;
                hv[4]=h2.x; hv[5]=h2.y; hv[6]=h3.x; hv[7]=h3.y;
                lv[0]=g0.x; lv[1]=g0.y; lv[2]=g1.x; lv[3]=g1.y;
                lv[4]=g2.x; lv[5]=g2.y; lv[6]=g3.x; lv[7]=g3.y;
                *(half8_t*)&Kh[skey][sd0 + g * 8] = hv;
                *(half8_t*)&Kl[skey][sd0 + g * 8] = lv;
            }
        }
        // ---- stage V transposed (fp16 hi/lo) ----
        {
            const int j0 = k0 + 2 * vkp, j1 = j0 + 1;
            const float* r0 = nullptr;
            const float* r1 = nullptr;
            if (j0 < nk)
                r0 = (j0 < start) ? (vcache + (size_t)j0 * DIM + nHD + vd0)
                                  : (vnew + (size_t)(j0 - start) * DIM + nHD + vd0);
            if (j1 < nk)
                r1 = (j1 < start) ? (vcache + (size_t)j1 * DIM + nHD + vd0)
                                  : (vnew + (size_t)(j1 - start) * DIM + nHD + vd0);
            float A[16], B[16];
            #pragma unroll
            for (int g = 0; g < 4; ++g) {
                float4 a = r0 ? *(const float4*)(r0 + g * 4) : make_float4(0, 0, 0, 0);
                float4 b = r1 ? *(const float4*)(r1 + g * 4) : make_float4(0, 0, 0, 0);
                A[g*4+0]=a.x; A[g*4+1]=a.y; A[g*4+2]=a.z; A[g*4+3]=a.w;
                B[g*4+0]=b.x; B[g*4+1]=b.y; B[g*4+2]=b.z; B[g*4+3]=b.w;
            }
            #pragma unroll
            for (int j = 0; j < 16; ++j) {
                half2_t hh = pkrtz(A[j], B[j]);
                half2_t ll = pkrtz(A[j] - (float)hh.x, B[j] - (float)hh.y);
                *(half2_t*)&Vth[vd0 + j][2 * vkp] = hh;
                *(half2_t*)&Vtl[vd0 + j][2 * vkp] = ll;
            }
        }
        __syncthreads();

        // ---- S = Q K^T (split fp16 MFMA) ----
        f32x4 sacc[2][2];
        #pragma unroll
        for (int qs = 0; qs < 2; ++qs)
            #pragma unroll
            for (int ks = 0; ks < 2; ++ks) sacc[qs][ks] = (f32x4){0.f, 0.f, 0.f, 0.f};
        #pragma unroll
        for (int ks = 0; ks < 2; ++ks) {
            #pragma unroll
            for (int db = 0; db < 4; ++db) {
                half8_t bh = *(const half8_t*)&Kh[ks * 16 + l16][db * 32 + quad * 8];
                half8_t bl = *(const half8_t*)&Kl[ks * 16 + l16][db * 32 + quad * 8];
                #pragma unroll
                for (int qs = 0; qs < 2; ++qs) {
                    sacc[qs][ks] = __builtin_amdgcn_mfma_f32_16x16x32_f16(qh[qs][db], bh, sacc[qs][ks], 0, 0, 0);
                    sacc[qs][ks] = __builtin_amdgcn_mfma_f32_16x16x32_f16(qh[qs][db], bl, sacc[qs][ks], 0, 0, 0);
                    sacc[qs][ks] = __builtin_amdgcn_mfma_f32_16x16x32_f16(ql[qs][db], bh, sacc[qs][ks], 0, 0, 0);
                }
            }
        }

        // ---- online softmax (C-layout: col=l16=key, row=quad*4+r=q) ----
        const bool v0 = (k0 + l16) < nk;
        const bool v1 = (k0 + 16 + l16) < nk;
        #pragma unroll
        for (int qs = 0; qs < 2; ++qs) {
            #pragma unroll
            for (int r = 0; r < 4; ++r) {
                float s0 = v0 ? sacc[qs][0][r] * sc : -1e30f;
                float s1 = v1 ? sacc[qs][1][r] * sc : -1e30f;
                float mx = fmaxf(s0, s1);
                #pragma unroll
                for (int d = 1; d < 16; d <<= 1) mx = fmaxf(mx, __shfl_xor(mx, d));
                float mn = fmaxf(mrow[qs][r], mx);
                float al = __expf(mrow[qs][r] - mn);
                mrow[qs][r] = mn;
                float p0 = __expf(s0 - mn);
                float p1 = __expf(s1 - mn);
                float ps = p0 + p1;
                #pragma unroll
                for (int d = 1; d < 16; d <<= 1) ps += __shfl_xor(ps, d);
                lrow[qs][r] = lrow[qs][r] * al + ps;
                const int prow = qs * 16 + quad * 4 + r;
                Pf[wave][prow][l16] = p0;
                Pf[wave][prow][16 + l16] = p1;
                #pragma unroll
                for (int ds = 0; ds < 8; ++ds) O[qs][ds][r] *= al;
            }
        }

        // ---- P -> A-layout via LDS, split to fp16 hi/lo ----
        half8_t ph[2], pl[2];
        #pragma unroll
        for (int qs = 0; qs < 2; ++qs) {
            const float* pr = &Pf[wave][qs * 16 + l16][quad * 8];
            float4 a = *(const float4*)pr;
            float4 b = *(const float4*)(pr + 4);
            half2_t h0 = pkrtz(a.x, a.y), h1 = pkrtz(a.z, a.w);
            half2_t h2 = pkrtz(b.x, b.y), h3 = pkrtz(b.z, b.w);
            half2_t g0 = pkrtz(a.x - (float)h0.x, a.y - (float)h0.y);
            half2_t g1 = pkrtz(a.z - (float)h1.x, a.w - (float)h1.y);
            half2_t g2 = pkrtz(b.x - (float)h2.x, b.y - (float)h2.y);
            half2_t g3 = pkrtz(b.z - (float)h3.x, b.w - (float)h3.y);
            half8_t hv, lv;
            hv[0]=h0.x; hv[1]=h0.y; hv[2]=h1.x; hv[3]=h1.y;
            hv[4]=h2.x; hv[5]=h2.y; hv[6]=h3.x; hv[7]=h3.y;
            lv[0]=g0.x; lv[1]=g0.y; lv[2]=g1.x; lv[3]=g1.y;
            lv[4]=g2.x; lv[5]=g2.y; lv[6]=g3.x; lv[7]=g3.y;
            ph[qs] = hv; pl[qs] = lv;
        }

        // ---- O += P V (split fp16 MFMA); B-frags shared across q-subtiles ----
        #pragma unroll
        for (int ds = 0; ds < 8; ++ds) {
            half8_t vh = *(const half8_t*)&Vth[ds * 16 + l16][quad * 8];
            half8_t vl = *(const half8_t*)&Vtl[ds * 16 + l16][quad * 8];
            #pragma unroll
            for (int qs = 0; qs < 2; ++qs) {
                O[qs][ds] = __builtin_amdgcn_mfma_f32_16x16x32_f16(ph[qs], vh, O[qs][ds], 0, 0, 0);
                O[qs][ds] = __builtin_amdgcn_mfma_f32_16x16x32_f16(ph[qs], vl, O[qs][ds], 0, 0, 0);
                O[qs][ds] = __builtin_amdgcn_mfma_f32_16x16x32_f16(pl[qs], vh, O[qs][ds], 0, 0, 0);
            }
        }
    }

    // ---- epilogue ----
    #pragma unroll
    for (int qs = 0; qs < 2; ++qs) {
        #pragma unroll
        for (int r = 0; r < 4; ++r) {
            const int row = q0 + wave * 32 + qs * 16 + quad * 4 + r;
            if (row < S) {
                const float inv = 1.f / lrow[qs][r];
                float* op = o + (size_t)row * DIM + nHD + l16;
                #pragma unroll
                for (int ds = 0; ds < 8; ++ds) op[ds * 16] = O[qs][ds][r] * inv;
            }
        }
    }
}

extern "C" void kernel_launch(void* const* d_in, const int* in_sizes, int n_in,
                              void* d_out, int out_size, void* d_ws, size_t ws_size,
                              hipStream_t stream)
{
    const float* x      = (const float*)d_in[0];
    const float* wq     = (const float*)d_in[1];
    const float* bq     = (const float*)d_in[2];
    const float* wk     = (const float*)d_in[3];
    const float* bk     = (const float*)d_in[4];
    const float* wv     = (const float*)d_in[5];
    const float* bv     = (const float*)d_in[6];
    const float* wo     = (const float*)d_in[7];
    const float* bo     = (const float*)d_in[8];
    const float* nqw    = (const float*)d_in[9];
    const float* nkw    = (const float*)d_in[10];
    const float* freqs  = (const float*)d_in[11];
    const float* kcache = (const float*)d_in[12];
    const float* vcache = (const float*)d_in[13];
    const int*   fp     = (const int*)d_in[14];
    const int*   hp     = (const int*)d_in[15];
    const int*   wp     = (const int*)d_in[16];
    const int*   gip    = (const int*)d_in[17];

    const int S = in_sizes[0] / DIM;

    float* q = (float*)d_ws;                 // S*DIM
    float* k = q + (size_t)S * DIM;          // S*DIM
    float* v = k + (size_t)S * DIM;          // S*DIM
    float* o = v + (size_t)S * DIM;          // S*DIM
    float* out = (float*)d_out;

    dim3 blk(256);
    dim3 ggrid(DIM / 64, (S + 63) / 64);
    gemm_bias_tn<<<ggrid, blk, 0, stream>>>(x, wq, bq, q, S, DIM, DIM);
    gemm_bias_tn<<<ggrid, blk, 0, stream>>>(x, wk, bk, k, S, DIM, DIM);
    gemm_bias_tn<<<ggrid, blk, 0, stream>>>(x, wv, bv, v, S, DIM, DIM);
    rms_rope_kernel<<<dim3(S), blk, 0, stream>>>(q, nqw, freqs, fp, hp, wp, gip);
    rms_rope_kernel<<<dim3(S), blk, 0, stream>>>(k, nkw, freqs, fp, hp, wp, gip);
    attn_mfma<<<dim3(NH, (S + 63) / 64), dim3(128), 0, stream>>>(q, k, v, kcache, vcache, o, S, gip);
    gemm_bias_tn<<<ggrid, blk, 0, stream>>>(o, wo, bo, out, S, DIM, DIM);
}

// Round 4
// 1011.878 us; speedup vs baseline: 5.9497x; 2.7146x over previous
//
#include <hip/hip_runtime.h>

#define DIM 1536
#define NH 12
#define HD 128
#define KSPLIT 4

typedef _Float16 half2_t __attribute__((ext_vector_type(2)));
typedef _Float16 half8_t __attribute__((ext_vector_type(8)));
typedef float f32x4 __attribute__((ext_vector_type(4)));

__device__ __forceinline__ half2_t pkrtz(float a, float b) {
    return __builtin_bit_cast(half2_t, __builtin_amdgcn_cvt_pkrtz(a, b));
}

// convert 8 f32 (two float4) into hi/lo half8
__device__ __forceinline__ void split8(float4 a, float4 b, half8_t& h, half8_t& l) {
    half2_t h0 = pkrtz(a.x, a.y), h1 = pkrtz(a.z, a.w);
    half2_t h2 = pkrtz(b.x, b.y), h3 = pkrtz(b.z, b.w);
    half2_t g0 = pkrtz(a.x - (float)h0.x, a.y - (float)h0.y);
    half2_t g1 = pkrtz(a.z - (float)h1.x, a.w - (float)h1.y);
    half2_t g2 = pkrtz(b.x - (float)h2.x, b.y - (float)h2.y);
    half2_t g3 = pkrtz(b.z - (float)h3.x, b.w - (float)h3.y);
    h[0]=h0.x; h[1]=h0.y; h[2]=h1.x; h[3]=h1.y; h[4]=h2.x; h[5]=h2.y; h[6]=h3.x; h[7]=h3.y;
    l[0]=g0.x; l[1]=g0.y; l[2]=g1.x; l[3]=g1.y; l[4]=g2.x; l[5]=g2.y; l[6]=g3.x; l[7]=g3.y;
}

// ---------------- split-fp16 MFMA GEMM: C[M,1536] = A[M,1536] @ B[1536,1536]^T + bias ----
// Handles up to 3 fused output matrices (blockIdx.x selects): used for fused QKV and out-proj.
#define ASTR 40
__global__ __launch_bounds__(256) void gemm_mfma_tn(
    const float* __restrict__ A,
    const float* __restrict__ B0, const float* __restrict__ B1, const float* __restrict__ B2,
    const float* __restrict__ bias0, const float* __restrict__ bias1, const float* __restrict__ bias2,
    float* __restrict__ C0, float* __restrict__ C1, float* __restrict__ C2,
    int M)
{
    __shared__ __align__(16) _Float16 Ah[128][ASTR], Al[128][ASTR];
    __shared__ __align__(16) _Float16 Bh[128][ASTR], Bl[128][ASTR];
    const int bx = blockIdx.x, by = blockIdx.y;
    const int mat = bx / 12, nt = bx % 12;
    const float* B    = mat == 0 ? B0    : mat == 1 ? B1    : B2;
    const float* bias = mat == 0 ? bias0 : mat == 1 ? bias1 : bias2;
    float*       C    = mat == 0 ? C0    : mat == 1 ? C1    : C2;
    const int m0 = by * 128, n0 = nt * 128;
    const int tid = threadIdx.x;
    const int lane = tid & 63, wave = tid >> 6;
    const int l16 = lane & 15, quad = lane >> 4;
    const int wm = (wave >> 1) * 64, wn = (wave & 1) * 64;
    const int srow = tid >> 1;
    const int scol = (tid & 1) * 16;
    const int am = m0 + srow;
    const bool avalid = am < M;
    const float* ap = A + (size_t)(avalid ? am : 0) * DIM + scol;
    const float* bp = B + (size_t)(n0 + srow) * DIM + scol;

    f32x4 acc[4][4];
    #pragma unroll
    for (int i = 0; i < 4; ++i)
        #pragma unroll
        for (int j = 0; j < 4; ++j) acc[i][j] = (f32x4){0.f, 0.f, 0.f, 0.f};

    for (int kk = 0; kk < DIM; kk += 32) {
        __syncthreads();
        #pragma unroll
        for (int g = 0; g < 2; ++g) {
            float4 a0 = make_float4(0,0,0,0), a1 = a0;
            if (avalid) { a0 = *(const float4*)(ap + kk + g*8); a1 = *(const float4*)(ap + kk + g*8 + 4); }
            half8_t h, l; split8(a0, a1, h, l);
            *(half8_t*)&Ah[srow][scol + g*8] = h;
            *(half8_t*)&Al[srow][scol + g*8] = l;
            float4 b0 = *(const float4*)(bp + kk + g*8);
            float4 b1 = *(const float4*)(bp + kk + g*8 + 4);
            split8(b0, b1, h, l);
            *(half8_t*)&Bh[srow][scol + g*8] = h;
            *(half8_t*)&Bl[srow][scol + g*8] = l;
        }
        __syncthreads();
        half8_t ah[4], al[4], bh[4], bl[4];
        #pragma unroll
        for (int ms = 0; ms < 4; ++ms) {
            ah[ms] = *(const half8_t*)&Ah[wm + ms*16 + l16][quad*8];
            al[ms] = *(const half8_t*)&Al[wm + ms*16 + l16][quad*8];
        }
        #pragma unroll
        for (int ns = 0; ns < 4; ++ns) {
            bh[ns] = *(const half8_t*)&Bh[wn + ns*16 + l16][quad*8];
            bl[ns] = *(const half8_t*)&Bl[wn + ns*16 + l16][quad*8];
        }
        #pragma unroll
        for (int ms = 0; ms < 4; ++ms)
            #pragma unroll
            for (int ns = 0; ns < 4; ++ns) {
                acc[ms][ns] = __builtin_amdgcn_mfma_f32_16x16x32_f16(ah[ms], bh[ns], acc[ms][ns], 0, 0, 0);
                acc[ms][ns] = __builtin_amdgcn_mfma_f32_16x16x32_f16(ah[ms], bl[ns], acc[ms][ns], 0, 0, 0);
                acc[ms][ns] = __builtin_amdgcn_mfma_f32_16x16x32_f16(al[ms], bh[ns], acc[ms][ns], 0, 0, 0);
            }
    }
    float bv[4];
    #pragma unroll
    for (int ns = 0; ns < 4; ++ns) bv[ns] = bias[n0 + wn + ns*16 + l16];
    #pragma unroll
    for (int ms = 0; ms < 4; ++ms)
        #pragma unroll
        for (int r = 0; r < 4; ++r) {
            const int row = m0 + wm + ms*16 + quad*4 + r;
            if (row < M) {
                #pragma unroll
                for (int ns = 0; ns < 4; ++ns)
                    C[(size_t)row * DIM + n0 + wn + ns*16 + l16] = acc[ms][ns][r] + bv[ns];
            }
        }
}

// ---------------- RMSNorm + 3D RoPE (in-place, f32) ----------------
__global__ __launch_bounds__(256) void rms_rope_kernel(
    float* __restrict__ x, const float* __restrict__ w,
    const float* __restrict__ freqs,
    const int* __restrict__ fp, const int* __restrict__ hp,
    const int* __restrict__ wp, const int* __restrict__ gip)
{
    const int s = blockIdx.x;
    const int tid = threadIdx.x;
    float* row = x + (size_t)s * DIM;
    float ss = 0.f;
    for (int c = tid; c < DIM; c += 256) { float v = row[c]; ss += v * v; }
    #pragma unroll
    for (int off = 32; off > 0; off >>= 1) ss += __shfl_down(ss, off, 64);
    __shared__ float red[4];
    if ((tid & 63) == 0) red[tid >> 6] = ss;
    __syncthreads();
    const float tot = red[0] + red[1] + red[2] + red[3];
    const float scale = rsqrtf(tot / (float)DIM + 1e-6f);
    const int f = *fp, h = *hp, ww = *wp, gi = *gip;
    const int hw = h * ww;
    const int fi = s / hw;
    const int rem = s - fi * hw;
    const int hi = rem / ww;
    const int wi = rem - hi * ww;
    const int sf = gi * f;
    for (int p = tid; p < DIM / 2; p += 256) {
        int n = p >> 6, i = p & 63;
        int pos = (i < 22) ? (sf + fi) : (i < 43) ? hi : wi;
        float cs = freqs[pos * 128 + i * 2];
        float sn = freqs[pos * 128 + i * 2 + 1];
        int base = n * HD + 2 * i;
        float x0 = row[base] * scale * w[base];
        float x1 = row[base + 1] * scale * w[base + 1];
        row[base] = x0 * cs - x1 * sn;
        row[base + 1] = x0 * sn + x1 * cs;
    }
}

// ---------------- MFMA flash attention, split-K partials ----------------
// 256 threads = 4 waves; wave handles 16 q-rows; block = 64 q-rows, one head, one K-split.
#define KT 32
#define KSTR 136
#define VSTR 40
#define PSTR 36

__global__ __launch_bounds__(256) void attn_mfma(
    const float* __restrict__ q, const float* __restrict__ knew,
    const float* __restrict__ vnew, const float* __restrict__ kcache,
    const float* __restrict__ vcache, float* __restrict__ Op,
    float* __restrict__ Ml, int S, const int* __restrict__ gip)
{
    __shared__ __align__(16) _Float16 Kh[KT][KSTR], Kl[KT][KSTR];
    __shared__ __align__(16) _Float16 Vth[HD][VSTR], Vtl[HD][VSTR];
    __shared__ __align__(16) float Pf[4][16][PSTR];

    const int n = blockIdx.x;           // head
    const int q0 = blockIdx.y * 64;     // q-tile base
    const int ks = blockIdx.z;          // K-split
    const int tid = threadIdx.x;
    const int wave = tid >> 6;
    const int lane = tid & 63;
    const int l16 = lane & 15;
    const int quad = lane >> 4;
    const int nHD = n * HD;
    const int start = gip[0] * S;
    const int nk = start + S;
    const int chunk = (nk + KSPLIT - 1) / KSPLIT;
    const int kbeg = ks * chunk;
    const int kend = min(kbeg + chunk, nk);
    const float sc = 0.08838834764831845f;  // 1/sqrt(128)

    // ---- Q fragments (register-resident fp16 hi/lo) ----
    half8_t qh[4], ql[4];
    {
        const int qrow = q0 + wave * 16 + l16;
        const bool qv = qrow < S;
        const float* qp = q + (size_t)(qv ? qrow : 0) * DIM + nHD + quad * 8;
        #pragma unroll
        for (int db = 0; db < 4; ++db) {
            float4 a = make_float4(0,0,0,0), b = a;
            if (qv) { a = *(const float4*)(qp + db * 32); b = *(const float4*)(qp + db * 32 + 4); }
            split8(a, b, qh[db], ql[db]);
        }
    }

    f32x4 O[8];
    #pragma unroll
    for (int ds = 0; ds < 8; ++ds) O[ds] = (f32x4){0.f, 0.f, 0.f, 0.f};
    float mrow[4], lrow[4];
    #pragma unroll
    for (int r = 0; r < 4; ++r) { mrow[r] = -1e30f; lrow[r] = 0.f; }

    // staging coords (256 threads)
    const int skey = tid >> 3;          // 0..31
    const int sd0  = (tid & 7) * 16;    // K: 16-dim chunk
    const int vk   = tid & 31;          // V: key
    const int vd0  = (tid >> 5) * 16;   // V: 16-dim chunk

    for (int k0 = kbeg; k0 < kend; k0 += KT) {
        __syncthreads();
        // ---- stage K ----
        {
            const int kj = k0 + skey;
            const float* kr = nullptr;
            if (kj < kend)
                kr = (kj < start) ? (kcache + (size_t)kj * DIM + nHD + sd0)
                                  : (knew + (size_t)(kj - start) * DIM + nHD + sd0);
            #pragma unroll
            for (int g = 0; g < 2; ++g) {
                float4 a = make_float4(0,0,0,0), b = a;
                if (kr) { a = *(const float4*)(kr + g*8); b = *(const float4*)(kr + g*8 + 4); }
                half8_t h, l; split8(a, b, h, l);
                *(half8_t*)&Kh[skey][sd0 + g*8] = h;
                *(half8_t*)&Kl[skey][sd0 + g*8] = l;
            }
        }
        // ---- stage V transposed ----
        {
            const int j = k0 + vk;
            const float* vr = nullptr;
            if (j < kend)
                vr = (j < start) ? (vcache + (size_t)j * DIM + nHD + vd0)
                                 : (vnew + (size_t)(j - start) * DIM + nHD + vd0);
            float V[16];
            #pragma unroll
            for (int g = 0; g < 4; ++g) {
                float4 a = vr ? *(const float4*)(vr + g*4) : make_float4(0,0,0,0);
                V[g*4+0]=a.x; V[g*4+1]=a.y; V[g*4+2]=a.z; V[g*4+3]=a.w;
            }
            #pragma unroll
            for (int jj = 0; jj < 16; ++jj) {
                _Float16 hh = (_Float16)V[jj];
                Vth[vd0 + jj][vk] = hh;
                Vtl[vd0 + jj][vk] = (_Float16)(V[jj] - (float)hh);
            }
        }
        __syncthreads();

        // ---- S = Q K^T ----
        f32x4 sacc[2];
        sacc[0] = (f32x4){0.f,0.f,0.f,0.f};
        sacc[1] = (f32x4){0.f,0.f,0.f,0.f};
        #pragma unroll
        for (int kss = 0; kss < 2; ++kss) {
            #pragma unroll
            for (int db = 0; db < 4; ++db) {
                half8_t bh = *(const half8_t*)&Kh[kss*16 + l16][db*32 + quad*8];
                half8_t bl = *(const half8_t*)&Kl[kss*16 + l16][db*32 + quad*8];
                sacc[kss] = __builtin_amdgcn_mfma_f32_16x16x32_f16(qh[db], bh, sacc[kss], 0, 0, 0);
                sacc[kss] = __builtin_amdgcn_mfma_f32_16x16x32_f16(qh[db], bl, sacc[kss], 0, 0, 0);
                sacc[kss] = __builtin_amdgcn_mfma_f32_16x16x32_f16(ql[db], bh, sacc[kss], 0, 0, 0);
            }
        }

        // ---- online softmax (C-layout: col=l16=key, row=quad*4+r) ----
        const bool v0 = (k0 + l16) < kend;
        const bool v1 = (k0 + 16 + l16) < kend;
        #pragma unroll
        for (int r = 0; r < 4; ++r) {
            float s0 = v0 ? sacc[0][r] * sc : -1e30f;
            float s1 = v1 ? sacc[1][r] * sc : -1e30f;
            float mx = fmaxf(s0, s1);
            #pragma unroll
            for (int d = 1; d < 16; d <<= 1) mx = fmaxf(mx, __shfl_xor(mx, d));
            float mn = fmaxf(mrow[r], mx);
            float al = __expf(mrow[r] - mn);
            mrow[r] = mn;
            float p0 = __expf(s0 - mn);
            float p1 = __expf(s1 - mn);
            float ps = p0 + p1;
            #pragma unroll
            for (int d = 1; d < 16; d <<= 1) ps += __shfl_xor(ps, d);
            lrow[r] = lrow[r] * al + ps;
            const int prow = quad * 4 + r;
            Pf[wave][prow][l16] = p0;
            Pf[wave][prow][16 + l16] = p1;
            #pragma unroll
            for (int ds = 0; ds < 8; ++ds) O[ds][r] *= al;
        }

        // ---- P -> A-layout (wave-private LDS round-trip) ----
        half8_t ph, pl;
        {
            const float* pr = &Pf[wave][l16][quad*8];
            float4 a = *(const float4*)pr;
            float4 b = *(const float4*)(pr + 4);
            split8(a, b, ph, pl);
        }

        // ---- O += P V ----
        #pragma unroll
        for (int ds = 0; ds < 8; ++ds) {
            half8_t vh = *(const half8_t*)&Vth[ds*16 + l16][quad*8];
            half8_t vl = *(const half8_t*)&Vtl[ds*16 + l16][quad*8];
            O[ds] = __builtin_amdgcn_mfma_f32_16x16x32_f16(ph, vh, O[ds], 0, 0, 0);
            O[ds] = __builtin_amdgcn_mfma_f32_16x16x32_f16(ph, vl, O[ds], 0, 0, 0);
            O[ds] = __builtin_amdgcn_mfma_f32_16x16x32_f16(pl, vh, O[ds], 0, 0, 0);
        }
    }

    // ---- write partials (unnormalized O, m, l) ----
    #pragma unroll
    for (int r = 0; r < 4; ++r) {
        const int row = q0 + wave * 16 + quad * 4 + r;
        if (row < S) {
            float* op = Op + (((size_t)ks * NH + n) * S + row) * HD + l16;
            #pragma unroll
            for (int ds = 0; ds < 8; ++ds) op[ds * 16] = O[ds][r];
            if (l16 == 0) {
                float* ml = Ml + (((size_t)ks * NH + n) * S + row) * 2;
                ml[0] = mrow[r];
                ml[1] = lrow[r];
            }
        }
    }
}

// ---------------- merge split-K partials ----------------
__global__ __launch_bounds__(256) void attn_merge(
    const float* __restrict__ Op, const float* __restrict__ Ml,
    float* __restrict__ o, int S)
{
    const int idx = blockIdx.x * 256 + threadIdx.x;
    const int total = NH * S * HD;
    if (idx >= total) return;
    const int d = idx & (HD - 1);
    const int t = idx >> 7;
    const int row = t % S;
    const int n = t / S;
    float m = -1e30f;
    #pragma unroll
    for (int ks = 0; ks < KSPLIT; ++ks)
        m = fmaxf(m, Ml[(((size_t)ks * NH + n) * S + row) * 2]);
    float num = 0.f, den = 0.f;
    #pragma unroll
    for (int ks = 0; ks < KSPLIT; ++ks) {
        const size_t base = ((size_t)ks * NH + n) * S + row;
        float w = __expf(Ml[base * 2] - m);
        num += w * Op[base * HD + d];
        den += w * Ml[base * 2 + 1];
    }
    o[(size_t)row * DIM + n * HD + d] = num / den;
}

extern "C" void kernel_launch(void* const* d_in, const int* in_sizes, int n_in,
                              void* d_out, int out_size, void* d_ws, size_t ws_size,
                              hipStream_t stream)
{
    const float* x      = (const float*)d_in[0];
    const float* wq     = (const float*)d_in[1];
    const float* bq     = (const float*)d_in[2];
    const float* wk     = (const float*)d_in[3];
    const float* bk     = (const float*)d_in[4];
    const float* wv     = (const float*)d_in[5];
    const float* bv     = (const float*)d_in[6];
    const float* wo     = (const float*)d_in[7];
    const float* bo     = (const float*)d_in[8];
    const float* nqw    = (const float*)d_in[9];
    const float* nkw    = (const float*)d_in[10];
    const float* freqs  = (const float*)d_in[11];
    const float* kcache = (const float*)d_in[12];
    const float* vcache = (const float*)d_in[13];
    const int*   fp     = (const int*)d_in[14];
    const int*   hp     = (const int*)d_in[15];
    const int*   wp     = (const int*)d_in[16];
    const int*   gip    = (const int*)d_in[17];

    const int S = in_sizes[0] / DIM;
    const size_t sd = (size_t)S * DIM;

    float* q  = (float*)d_ws;          // S*DIM
    float* k  = q + sd;                // S*DIM
    float* v  = k + sd;                // S*DIM
    float* o  = v + sd;                // S*DIM
    float* Op = o + sd;                // KSPLIT*NH*S*HD
    float* Ml = Op + (size_t)KSPLIT * NH * S * HD;  // KSPLIT*NH*S*2
    float* out = (float*)d_out;

    const int mt = (S + 127) / 128;    // m-tiles
    // fused QKV projection
    gemm_mfma_tn<<<dim3(36, mt), dim3(256), 0, stream>>>(
        x, wq, wk, wv, bq, bk, bv, q, k, v, S);
    rms_rope_kernel<<<dim3(S), dim3(256), 0, stream>>>(q, nqw, freqs, fp, hp, wp, gip);
    rms_rope_kernel<<<dim3(S), dim3(256), 0, stream>>>(k, nkw, freqs, fp, hp, wp, gip);
    attn_mfma<<<dim3(NH, (S + 63) / 64, KSPLIT), dim3(256), 0, stream>>>(
        q, k, v, kcache, vcache, Op, Ml, S, gip);
    attn_merge<<<dim3((NH * S * HD + 255) / 256), dim3(256), 0, stream>>>(Op, Ml, o, S);
    // output projection
    gemm_mfma_tn<<<dim3(12, mt), dim3(256), 0, stream>>>(
        o, wo, wo, wo, bo, bo, bo, out, out, out, S);
}

// Round 5
// 686.837 us; speedup vs baseline: 8.7653x; 1.4732x over previous
//
#include <hip/hip_runtime.h>

#define DIM 1536
#define NH 12
#define HD 128
#define KSPLIT 4
#define KT 32
#define MFIX 3.0f

typedef _Float16 half2_t __attribute__((ext_vector_type(2)));
typedef _Float16 half8_t __attribute__((ext_vector_type(8)));
typedef float f32x4 __attribute__((ext_vector_type(4)));

__device__ __forceinline__ half2_t pkrtz(float a, float b) {
    return __builtin_bit_cast(half2_t, __builtin_amdgcn_cvt_pkrtz(a, b));
}

// convert 8 f32 (two float4) into hi/lo half8
__device__ __forceinline__ void split8(float4 a, float4 b, half8_t& h, half8_t& l) {
    half2_t h0 = pkrtz(a.x, a.y), h1 = pkrtz(a.z, a.w);
    half2_t h2 = pkrtz(b.x, b.y), h3 = pkrtz(b.z, b.w);
    half2_t g0 = pkrtz(a.x - (float)h0.x, a.y - (float)h0.y);
    half2_t g1 = pkrtz(a.z - (float)h1.x, a.w - (float)h1.y);
    half2_t g2 = pkrtz(b.x - (float)h2.x, b.y - (float)h2.y);
    half2_t g3 = pkrtz(b.z - (float)h3.x, b.w - (float)h3.y);
    h[0]=h0.x; h[1]=h0.y; h[2]=h1.x; h[3]=h1.y; h[4]=h2.x; h[5]=h2.y; h[6]=h3.x; h[7]=h3.y;
    l[0]=g0.x; l[1]=g0.y; l[2]=g1.x; l[3]=g1.y; l[4]=g2.x; l[5]=g2.y; l[6]=g3.x; l[7]=g3.y;
}

// ---------------- split-fp16 MFMA GEMM: C[M,1536] = A[M,1536] @ B[1536,1536]^T + bias ----
#define ASTR 40
__global__ __launch_bounds__(256) void gemm_mfma_tn(
    const float* __restrict__ A,
    const float* __restrict__ B0, const float* __restrict__ B1, const float* __restrict__ B2,
    const float* __restrict__ bias0, const float* __restrict__ bias1, const float* __restrict__ bias2,
    float* __restrict__ C0, float* __restrict__ C1, float* __restrict__ C2,
    int M)
{
    __shared__ __align__(16) _Float16 Ah[128][ASTR], Al[128][ASTR];
    __shared__ __align__(16) _Float16 Bh[128][ASTR], Bl[128][ASTR];
    const int bx = blockIdx.x, by = blockIdx.y;
    const int mat = bx / 12, nt = bx % 12;
    const float* B    = mat == 0 ? B0    : mat == 1 ? B1    : B2;
    const float* bias = mat == 0 ? bias0 : mat == 1 ? bias1 : bias2;
    float*       C    = mat == 0 ? C0    : mat == 1 ? C1    : C2;
    const int m0 = by * 128, n0 = nt * 128;
    const int tid = threadIdx.x;
    const int lane = tid & 63, wave = tid >> 6;
    const int l16 = lane & 15, quad = lane >> 4;
    const int wm = (wave >> 1) * 64, wn = (wave & 1) * 64;
    const int srow = tid >> 1;
    const int scol = (tid & 1) * 16;
    const int am = m0 + srow;
    const bool avalid = am < M;
    const float* ap = A + (size_t)(avalid ? am : 0) * DIM + scol;
    const float* bp = B + (size_t)(n0 + srow) * DIM + scol;

    f32x4 acc[4][4];
    #pragma unroll
    for (int i = 0; i < 4; ++i)
        #pragma unroll
        for (int j = 0; j < 4; ++j) acc[i][j] = (f32x4){0.f, 0.f, 0.f, 0.f};

    for (int kk = 0; kk < DIM; kk += 32) {
        __syncthreads();
        #pragma unroll
        for (int g = 0; g < 2; ++g) {
            float4 a0 = make_float4(0,0,0,0), a1 = a0;
            if (avalid) { a0 = *(const float4*)(ap + kk + g*8); a1 = *(const float4*)(ap + kk + g*8 + 4); }
            half8_t h, l; split8(a0, a1, h, l);
            *(half8_t*)&Ah[srow][scol + g*8] = h;
            *(half8_t*)&Al[srow][scol + g*8] = l;
            float4 b0 = *(const float4*)(bp + kk + g*8);
            float4 b1 = *(const float4*)(bp + kk + g*8 + 4);
            split8(b0, b1, h, l);
            *(half8_t*)&Bh[srow][scol + g*8] = h;
            *(half8_t*)&Bl[srow][scol + g*8] = l;
        }
        __syncthreads();
        half8_t ah[4], al[4], bh[4], bl[4];
        #pragma unroll
        for (int ms = 0; ms < 4; ++ms) {
            ah[ms] = *(const half8_t*)&Ah[wm + ms*16 + l16][quad*8];
            al[ms] = *(const half8_t*)&Al[wm + ms*16 + l16][quad*8];
        }
        #pragma unroll
        for (int ns = 0; ns < 4; ++ns) {
            bh[ns] = *(const half8_t*)&Bh[wn + ns*16 + l16][quad*8];
            bl[ns] = *(const half8_t*)&Bl[wn + ns*16 + l16][quad*8];
        }
        #pragma unroll
        for (int ms = 0; ms < 4; ++ms)
            #pragma unroll
            for (int ns = 0; ns < 4; ++ns) {
                acc[ms][ns] = __builtin_amdgcn_mfma_f32_16x16x32_f16(ah[ms], bh[ns], acc[ms][ns], 0, 0, 0);
                acc[ms][ns] = __builtin_amdgcn_mfma_f32_16x16x32_f16(ah[ms], bl[ns], acc[ms][ns], 0, 0, 0);
                acc[ms][ns] = __builtin_amdgcn_mfma_f32_16x16x32_f16(al[ms], bh[ns], acc[ms][ns], 0, 0, 0);
            }
    }
    float bv[4];
    #pragma unroll
    for (int ns = 0; ns < 4; ++ns) bv[ns] = bias[n0 + wn + ns*16 + l16];
    #pragma unroll
    for (int ms = 0; ms < 4; ++ms)
        #pragma unroll
        for (int r = 0; r < 4; ++r) {
            const int row = m0 + wm + ms*16 + quad*4 + r;
            if (row < M) {
                #pragma unroll
                for (int ns = 0; ns < 4; ++ns)
                    C[(size_t)row * DIM + n0 + wn + ns*16 + l16] = acc[ms][ns][r] + bv[ns];
            }
        }
}

// ---------------- RMSNorm + 3D RoPE (in-place, f32) ----------------
__global__ __launch_bounds__(256) void rms_rope_kernel(
    float* __restrict__ x, const float* __restrict__ w,
    const float* __restrict__ freqs,
    const int* __restrict__ fp, const int* __restrict__ hp,
    const int* __restrict__ wp, const int* __restrict__ gip)
{
    const int s = blockIdx.x;
    const int tid = threadIdx.x;
    float* row = x + (size_t)s * DIM;
    float ss = 0.f;
    for (int c = tid; c < DIM; c += 256) { float v = row[c]; ss += v * v; }
    #pragma unroll
    for (int off = 32; off > 0; off >>= 1) ss += __shfl_down(ss, off, 64);
    __shared__ float red[4];
    if ((tid & 63) == 0) red[tid >> 6] = ss;
    __syncthreads();
    const float tot = red[0] + red[1] + red[2] + red[3];
    const float scale = rsqrtf(tot / (float)DIM + 1e-6f);
    const int f = *fp, h = *hp, ww = *wp, gi = *gip;
    const int hw = h * ww;
    const int fi = s / hw;
    const int rem = s - fi * hw;
    const int hi = rem / ww;
    const int wi = rem - hi * ww;
    const int sf = gi * f;
    for (int p = tid; p < DIM / 2; p += 256) {
        int n = p >> 6, i = p & 63;
        int pos = (i < 22) ? (sf + fi) : (i < 43) ? hi : wi;
        float cs = freqs[pos * 128 + i * 2];
        float sn = freqs[pos * 128 + i * 2 + 1];
        int base = n * HD + 2 * i;
        float x0 = row[base] * scale * w[base];
        float x1 = row[base + 1] * scale * w[base + 1];
        row[base] = x0 * cs - x1 * sn;
        row[base + 1] = x0 * sn + x1 * cs;
    }
}

// ---------------- K prep: fp16 hi/lo, MFMA-frag-linear tiles ----------------
// Khg/Klg layout: [head][tile][ (f*64+lane)*8 halves ], f = ks*4+db, tile block = 4096 halves.
__global__ __launch_bounds__(256) void khl_prep(
    const float* __restrict__ kws, const float* __restrict__ kcache,
    _Float16* __restrict__ Khg, _Float16* __restrict__ Klg,
    int S, int NT, const int* __restrict__ gip)
{
    const int t = blockIdx.x, n = blockIdx.y;
    const int tid = threadIdx.x;
    const int lane = tid & 63;
    const int l16 = lane & 15, quad = lane >> 4;
    const int start = gip[0] * S;
    const int nk = start + S;
    _Float16* outh = Khg + ((size_t)n * NT + t) * 4096;
    _Float16* outl = Klg + ((size_t)n * NT + t) * 4096;
    #pragma unroll
    for (int fi = 0; fi < 2; ++fi) {
        const int f = (tid >> 6) + fi * 4;
        const int ks = f >> 2, db = f & 3;
        const int j = t * KT + ks * 16 + l16;
        float4 a = make_float4(0,0,0,0), b = a;
        if (j < nk) {
            const float* src = (j < start) ? (kcache + (size_t)j * DIM)
                                           : (kws + (size_t)(j - start) * DIM);
            src += n * HD + db * 32 + quad * 8;
            a = *(const float4*)src;
            b = *(const float4*)(src + 4);
        }
        half8_t h, l; split8(a, b, h, l);
        *(half8_t*)&outh[(f * 64 + lane) * 8] = h;
        *(half8_t*)&outl[(f * 64 + lane) * 8] = l;
    }
}

// ---------------- V prep: fp16, transposed, frag-linear ----------------
// Vtg layout: [head][tile][ (ds*64+lane)*8 halves ]; frag element j = V[key=quad*8+j][dim=ds*16+l16]
__global__ __launch_bounds__(256) void vt_prep(
    const float* __restrict__ vws, const float* __restrict__ vcache,
    _Float16* __restrict__ Vtg, int S, int NT, const int* __restrict__ gip)
{
    const int t = blockIdx.x, n = blockIdx.y;
    const int tid = threadIdx.x;
    const int lane = tid & 63;
    const int l16 = lane & 15, quad = lane >> 4;
    const int start = gip[0] * S;
    const int nk = start + S;
    _Float16* out = Vtg + ((size_t)n * NT + t) * 4096;
    #pragma unroll
    for (int fi = 0; fi < 2; ++fi) {
        const int ds = (tid >> 6) + fi * 4;
        const int dim = n * HD + ds * 16 + l16;
        half8_t h;
        #pragma unroll
        for (int j = 0; j < 8; ++j) {
            const int key = t * KT + quad * 8 + j;
            float v = 0.f;
            if (key < nk)
                v = (key < start) ? vcache[(size_t)key * DIM + dim]
                                  : vws[(size_t)(key - start) * DIM + dim];
            h[j] = (_Float16)v;
        }
        *(half8_t*)&out[(ds * 64 + lane) * 8] = h;
    }
}

// ---------------- MFMA flash attention: fixed-max, frag-linear staging ----------------
#define PSTR 34
__global__ __launch_bounds__(256, 4) void attn_mfma(
    const float* __restrict__ q,
    const _Float16* __restrict__ Khg, const _Float16* __restrict__ Klg,
    const _Float16* __restrict__ Vtg,
    float* __restrict__ Op, float* __restrict__ Ml,
    int S, int NT, const int* __restrict__ gip)
{
    __shared__ __align__(16) _Float16 KhL[4096], KlL[4096], VtL[4096];
    __shared__ __align__(16) float Pf[4][16][PSTR];

    const int n = blockIdx.x;           // head
    const int q0 = blockIdx.y * 64;     // q-tile base
    const int ksp = blockIdx.z;         // K-split
    const int tid = threadIdx.x;
    const int wave = tid >> 6;
    const int lane = tid & 63;
    const int l16 = lane & 15;
    const int quad = lane >> 4;
    const int start = gip[0] * S;
    const int nk = start + S;
    const int totTiles = (nk + KT - 1) / KT;
    const int tilesPer = (totTiles + KSPLIT - 1) / KSPLIT;
    const int t0 = ksp * tilesPer;
    const int t1 = min(t0 + tilesPer, totTiles);
    const float sc = 0.08838834764831845f;  // 1/sqrt(128)

    // ---- Q fragments (register-resident fp16 hi/lo) ----
    half8_t qh[4], ql[4];
    {
        const int qrow = q0 + wave * 16 + l16;
        const bool qv = qrow < S;
        const float* qp = q + (size_t)(qv ? qrow : 0) * DIM + n * HD + quad * 8;
        #pragma unroll
        for (int db = 0; db < 4; ++db) {
            float4 a = make_float4(0,0,0,0), b = a;
            if (qv) { a = *(const float4*)(qp + db * 32); b = *(const float4*)(qp + db * 32 + 4); }
            split8(a, b, qh[db], ql[db]);
        }
    }

    // constant ones B-fragment: B[k][n] = (n==0) -> column 0 of 9th PV chunk = sum(P) = l
    half8_t ones_f;
    {
        _Float16 ov = (l16 == 0) ? (_Float16)1.0f : (_Float16)0.0f;
        #pragma unroll
        for (int j = 0; j < 8; ++j) ones_f[j] = ov;
    }

    f32x4 O[9];
    #pragma unroll
    for (int ds = 0; ds < 9; ++ds) O[ds] = (f32x4){0.f, 0.f, 0.f, 0.f};

    for (int t = t0; t < t1; ++t) {
        __syncthreads();
        // ---- stage K/V tiles: contiguous 8 KB copies (frag-linear, conflict-free) ----
        {
            const uint4* sKh = (const uint4*)(Khg + ((size_t)n * NT + t) * 4096);
            const uint4* sKl = (const uint4*)(Klg + ((size_t)n * NT + t) * 4096);
            const uint4* sV  = (const uint4*)(Vtg + ((size_t)n * NT + t) * 4096);
            #pragma unroll
            for (int c = 0; c < 2; ++c) {
                ((uint4*)KhL)[tid + c * 256] = sKh[tid + c * 256];
                ((uint4*)KlL)[tid + c * 256] = sKl[tid + c * 256];
                ((uint4*)VtL)[tid + c * 256] = sV[tid + c * 256];
            }
        }
        __syncthreads();

        // ---- S = Q K^T (split fp16: hh + hl + lh) ----
        f32x4 sacc[2];
        sacc[0] = (f32x4){0.f,0.f,0.f,0.f};
        sacc[1] = (f32x4){0.f,0.f,0.f,0.f};
        #pragma unroll
        for (int ks = 0; ks < 2; ++ks) {
            #pragma unroll
            for (int db = 0; db < 4; ++db) {
                half8_t bh = ((const half8_t*)KhL)[(ks*4 + db)*64 + lane];
                half8_t bl = ((const half8_t*)KlL)[(ks*4 + db)*64 + lane];
                sacc[ks] = __builtin_amdgcn_mfma_f32_16x16x32_f16(qh[db], bh, sacc[ks], 0, 0, 0);
                sacc[ks] = __builtin_amdgcn_mfma_f32_16x16x32_f16(qh[db], bl, sacc[ks], 0, 0, 0);
                sacc[ks] = __builtin_amdgcn_mfma_f32_16x16x32_f16(ql[db], bh, sacc[ks], 0, 0, 0);
            }
        }

        // ---- fixed-max softmax: p = exp(s*sc - MFIX), masked ----
        const int k0 = t * KT;
        const bool v0 = (k0 + l16) < nk;
        const bool v1 = (k0 + 16 + l16) < nk;
        #pragma unroll
        for (int r = 0; r < 4; ++r) {
            float p0 = v0 ? __expf(sacc[0][r] * sc - MFIX) : 0.f;
            float p1 = v1 ? __expf(sacc[1][r] * sc - MFIX) : 0.f;
            Pf[wave][quad * 4 + r][l16] = p0;
            Pf[wave][quad * 4 + r][16 + l16] = p1;
        }

        // ---- P -> A-layout via LDS (fp16, no lo) ----
        half8_t ph;
        {
            const float* pr = &Pf[wave][l16][quad * 8];
            float4 a = *(const float4*)pr;
            float4 b = *(const float4*)(pr + 4);
            half2_t h0 = pkrtz(a.x, a.y), h1 = pkrtz(a.z, a.w);
            half2_t h2 = pkrtz(b.x, b.y), h3 = pkrtz(b.z, b.w);
            ph[0]=h0.x; ph[1]=h0.y; ph[2]=h1.x; ph[3]=h1.y;
            ph[4]=h2.x; ph[5]=h2.y; ph[6]=h3.x; ph[7]=h3.y;
        }

        // ---- O += P V (fp16) + l via ones-frag ----
        #pragma unroll
        for (int ds = 0; ds < 8; ++ds) {
            half8_t vh = ((const half8_t*)VtL)[ds*64 + lane];
            O[ds] = __builtin_amdgcn_mfma_f32_16x16x32_f16(ph, vh, O[ds], 0, 0, 0);
        }
        O[8] = __builtin_amdgcn_mfma_f32_16x16x32_f16(ph, ones_f, O[8], 0, 0, 0);
    }

    // ---- write partials (unnormalized O, l) ----
    #pragma unroll
    for (int r = 0; r < 4; ++r) {
        const int row = q0 + wave * 16 + quad * 4 + r;
        if (row < S) {
            float* op = Op + (((size_t)ksp * NH + n) * S + row) * HD + l16;
            #pragma unroll
            for (int ds = 0; ds < 8; ++ds) op[ds * 16] = O[ds][r];
            if (l16 == 0)
                Ml[((size_t)ksp * NH + n) * S + row] = O[8][r];
        }
    }
}

// ---------------- merge split-K partials (fixed max -> plain sums) ----------------
__global__ __launch_bounds__(256) void attn_merge(
    const float* __restrict__ Op, const float* __restrict__ Ml,
    float* __restrict__ o, int S)
{
    const int idx = blockIdx.x * 256 + threadIdx.x;
    const int total = NH * S * HD;
    if (idx >= total) return;
    const int d = idx & (HD - 1);
    const int t = idx >> 7;
    const int row = t % S;
    const int n = t / S;
    float num = 0.f, den = 0.f;
    #pragma unroll
    for (int ks = 0; ks < KSPLIT; ++ks) {
        const size_t base = ((size_t)ks * NH + n) * S + row;
        num += Op[base * HD + d];
        den += Ml[base];
    }
    o[(size_t)row * DIM + n * HD + d] = num / den;
}

extern "C" void kernel_launch(void* const* d_in, const int* in_sizes, int n_in,
                              void* d_out, int out_size, void* d_ws, size_t ws_size,
                              hipStream_t stream)
{
    const float* x      = (const float*)d_in[0];
    const float* wq     = (const float*)d_in[1];
    const float* bq     = (const float*)d_in[2];
    const float* wk     = (const float*)d_in[3];
    const float* bk     = (const float*)d_in[4];
    const float* wv     = (const float*)d_in[5];
    const float* bv     = (const float*)d_in[6];
    const float* wo     = (const float*)d_in[7];
    const float* bo     = (const float*)d_in[8];
    const float* nqw    = (const float*)d_in[9];
    const float* nkw    = (const float*)d_in[10];
    const float* freqs  = (const float*)d_in[11];
    const float* kcache = (const float*)d_in[12];
    const float* vcache = (const float*)d_in[13];
    const int*   fp     = (const int*)d_in[14];
    const int*   hp     = (const int*)d_in[15];
    const int*   wp     = (const int*)d_in[16];
    const int*   gip    = (const int*)d_in[17];

    const int S = in_sizes[0] / DIM;
    const int total = in_sizes[12] / (NH * HD);   // k_cache rows (upper bound on nk)
    const int NT = (total + KT - 1) / KT;
    const size_t sd = (size_t)S * DIM;

    float* q  = (float*)d_ws;
    float* k  = q + sd;
    float* v  = k + sd;
    float* o  = v + sd;
    float* Op = o + sd;                              // KSPLIT*NH*S*HD
    float* Ml = Op + (size_t)KSPLIT * NH * S * HD;   // KSPLIT*NH*S
    _Float16* Khg = (_Float16*)(Ml + (size_t)KSPLIT * NH * S);
    _Float16* Klg = Khg + (size_t)NH * NT * 4096;
    _Float16* Vtg = Klg + (size_t)NH * NT * 4096;
    float* out = (float*)d_out;

    const int mt = (S + 127) / 128;
    // fused QKV projection
    gemm_mfma_tn<<<dim3(36, mt), dim3(256), 0, stream>>>(
        x, wq, wk, wv, bq, bk, bv, q, k, v, S);
    rms_rope_kernel<<<dim3(S), dim3(256), 0, stream>>>(q, nqw, freqs, fp, hp, wp, gip);
    rms_rope_kernel<<<dim3(S), dim3(256), 0, stream>>>(k, nkw, freqs, fp, hp, wp, gip);
    // K/V precompute into frag-linear fp16 tiles
    khl_prep<<<dim3(NT, NH), dim3(256), 0, stream>>>(k, kcache, Khg, Klg, S, NT, gip);
    vt_prep<<<dim3(NT, NH), dim3(256), 0, stream>>>(v, vcache, Vtg, S, NT, gip);
    // attention
    attn_mfma<<<dim3(NH, (S + 63) / 64, KSPLIT), dim3(256), 0, stream>>>(
        q, Khg, Klg, Vtg, Op, Ml, S, NT, gip);
    attn_merge<<<dim3((NH * S * HD + 255) / 256), dim3(256), 0, stream>>>(Op, Ml, o, S);
    // output projection
    gemm_mfma_tn<<<dim3(12, mt), dim3(256), 0, stream>>>(
        o, wo, wo, wo, bo, bo, bo, out, out, out, S);
}

// Round 6
// 628.105 us; speedup vs baseline: 9.5849x; 1.0935x over previous
//
#include <hip/hip_runtime.h>

#define DIM 1536
#define NH 12
#define HD 128
#define KSPLIT 4
#define KT 32
#define MFIX 3.0f

typedef _Float16 half2_t __attribute__((ext_vector_type(2)));
typedef _Float16 half8_t __attribute__((ext_vector_type(8)));
typedef float f32x4 __attribute__((ext_vector_type(4)));

__device__ __forceinline__ half2_t pkrtz(float a, float b) {
    return __builtin_bit_cast(half2_t, __builtin_amdgcn_cvt_pkrtz(a, b));
}

__device__ __forceinline__ void split8(float4 a, float4 b, half8_t& h, half8_t& l) {
    half2_t h0 = pkrtz(a.x, a.y), h1 = pkrtz(a.z, a.w);
    half2_t h2 = pkrtz(b.x, b.y), h3 = pkrtz(b.z, b.w);
    half2_t g0 = pkrtz(a.x - (float)h0.x, a.y - (float)h0.y);
    half2_t g1 = pkrtz(a.z - (float)h1.x, a.w - (float)h1.y);
    half2_t g2 = pkrtz(b.x - (float)h2.x, b.y - (float)h2.y);
    half2_t g3 = pkrtz(b.z - (float)h3.x, b.w - (float)h3.y);
    h[0]=h0.x; h[1]=h0.y; h[2]=h1.x; h[3]=h1.y; h[4]=h2.x; h[5]=h2.y; h[6]=h3.x; h[7]=h3.y;
    l[0]=g0.x; l[1]=g0.y; l[2]=g1.x; l[3]=g1.y; l[4]=g2.x; l[5]=g2.y; l[6]=g3.x; l[7]=g3.y;
}

// async global->LDS, 16 B per lane; lds must be wave-uniform, HW adds lane*16
__device__ __forceinline__ void gl2lds16(const void* g, void* l) {
    __builtin_amdgcn_global_load_lds(
        (const __attribute__((address_space(1))) unsigned int*)g,
        (__attribute__((address_space(3))) unsigned int*)(unsigned int)(uintptr_t)l,
        16, 0, 0);
}

// ---------------- f32 -> fp16 hi/lo flat conversion ----------------
__global__ __launch_bounds__(256) void cvt_hl(
    const float* __restrict__ src, _Float16* __restrict__ h, _Float16* __restrict__ l, int n8)
{
    const int i = blockIdx.x * 256 + threadIdx.x;
    if (i >= n8) return;
    const float4* s = (const float4*)src + (size_t)i * 2;
    float4 a = s[0], b = s[1];
    half8_t hh, ll; split8(a, b, hh, ll);
    ((half8_t*)h)[i] = hh;
    ((half8_t*)l)[i] = ll;
}

// ---------------- fp16 split GEMM: C[M,1536] = A @ B^T + bias (A,B pre-split hi/lo) ----
#define ASTR 40
__global__ __launch_bounds__(256) void gemm_f16_tn(
    const _Float16* __restrict__ Ah, const _Float16* __restrict__ Al,
    const _Float16* __restrict__ Bh0, const _Float16* __restrict__ Bl0,
    const _Float16* __restrict__ Bh1, const _Float16* __restrict__ Bl1,
    const _Float16* __restrict__ Bh2, const _Float16* __restrict__ Bl2,
    const float* __restrict__ bias0, const float* __restrict__ bias1, const float* __restrict__ bias2,
    float* __restrict__ C0, float* __restrict__ C1, float* __restrict__ C2,
    int M)
{
    __shared__ __align__(16) _Float16 AhL[128][ASTR], AlL[128][ASTR];
    __shared__ __align__(16) _Float16 BhL[128][ASTR], BlL[128][ASTR];
    const int bx = blockIdx.x, by = blockIdx.y;
    const int mat = bx / 12, nt = bx % 12;
    const _Float16* Bh   = mat == 0 ? Bh0 : mat == 1 ? Bh1 : Bh2;
    const _Float16* Bl   = mat == 0 ? Bl0 : mat == 1 ? Bl1 : Bl2;
    const float*    bias = mat == 0 ? bias0 : mat == 1 ? bias1 : bias2;
    float*          C    = mat == 0 ? C0 : mat == 1 ? C1 : C2;
    const int m0 = by * 128, n0 = nt * 128;
    const int tid = threadIdx.x;
    const int lane = tid & 63, wave = tid >> 6;
    const int l16 = lane & 15, quad = lane >> 4;
    const int wm = (wave >> 1) * 64, wn = (wave & 1) * 64;
    const int srow = tid >> 1;
    const int scol = (tid & 1) * 16;
    const bool avalid = (m0 + srow) < M;
    const _Float16* ahp = Ah + (size_t)(avalid ? m0 + srow : 0) * DIM + scol;
    const _Float16* alp = Al + (size_t)(avalid ? m0 + srow : 0) * DIM + scol;
    const _Float16* bhp = Bh + (size_t)(n0 + srow) * DIM + scol;
    const _Float16* blp = Bl + (size_t)(n0 + srow) * DIM + scol;

    f32x4 acc[4][4];
    #pragma unroll
    for (int i = 0; i < 4; ++i)
        #pragma unroll
        for (int j = 0; j < 4; ++j) acc[i][j] = (f32x4){0.f, 0.f, 0.f, 0.f};

    for (int kk = 0; kk < DIM; kk += 32) {
        __syncthreads();
        uint4 z = {0, 0, 0, 0};
        uint4 a0 = z, a1 = z, a2 = z, a3 = z;
        if (avalid) {
            a0 = *(const uint4*)(ahp + kk);
            a1 = *(const uint4*)(ahp + kk + 8);
            a2 = *(const uint4*)(alp + kk);
            a3 = *(const uint4*)(alp + kk + 8);
        }
        uint4 b0 = *(const uint4*)(bhp + kk);
        uint4 b1 = *(const uint4*)(bhp + kk + 8);
        uint4 b2 = *(const uint4*)(blp + kk);
        uint4 b3 = *(const uint4*)(blp + kk + 8);
        *(uint4*)&AhL[srow][scol]     = a0;
        *(uint4*)&AhL[srow][scol + 8] = a1;
        *(uint4*)&AlL[srow][scol]     = a2;
        *(uint4*)&AlL[srow][scol + 8] = a3;
        *(uint4*)&BhL[srow][scol]     = b0;
        *(uint4*)&BhL[srow][scol + 8] = b1;
        *(uint4*)&BlL[srow][scol]     = b2;
        *(uint4*)&BlL[srow][scol + 8] = b3;
        __syncthreads();
        half8_t ah[4], al[4], bh[4], bl[4];
        #pragma unroll
        for (int ms = 0; ms < 4; ++ms) {
            ah[ms] = *(const half8_t*)&AhL[wm + ms*16 + l16][quad*8];
            al[ms] = *(const half8_t*)&AlL[wm + ms*16 + l16][quad*8];
        }
        #pragma unroll
        for (int ns = 0; ns < 4; ++ns) {
            bh[ns] = *(const half8_t*)&BhL[wn + ns*16 + l16][quad*8];
            bl[ns] = *(const half8_t*)&BlL[wn + ns*16 + l16][quad*8];
        }
        #pragma unroll
        for (int ms = 0; ms < 4; ++ms)
            #pragma unroll
            for (int ns = 0; ns < 4; ++ns) {
                acc[ms][ns] = __builtin_amdgcn_mfma_f32_16x16x32_f16(ah[ms], bh[ns], acc[ms][ns], 0, 0, 0);
                acc[ms][ns] = __builtin_amdgcn_mfma_f32_16x16x32_f16(ah[ms], bl[ns], acc[ms][ns], 0, 0, 0);
                acc[ms][ns] = __builtin_amdgcn_mfma_f32_16x16x32_f16(al[ms], bh[ns], acc[ms][ns], 0, 0, 0);
            }
    }
    float bv[4];
    #pragma unroll
    for (int ns = 0; ns < 4; ++ns) bv[ns] = bias[n0 + wn + ns*16 + l16];
    #pragma unroll
    for (int ms = 0; ms < 4; ++ms)
        #pragma unroll
        for (int r = 0; r < 4; ++r) {
            const int row = m0 + wm + ms*16 + quad*4 + r;
            if (row < M) {
                #pragma unroll
                for (int ns = 0; ns < 4; ++ns)
                    C[(size_t)row * DIM + n0 + wn + ns*16 + l16] = acc[ms][ns][r] + bv[ns];
            }
        }
}

// ---------------- RMSNorm + 3D RoPE (in-place, f32) ----------------
__global__ __launch_bounds__(256) void rms_rope_kernel(
    float* __restrict__ x, const float* __restrict__ w,
    const float* __restrict__ freqs,
    const int* __restrict__ fp, const int* __restrict__ hp,
    const int* __restrict__ wp, const int* __restrict__ gip)
{
    const int s = blockIdx.x;
    const int tid = threadIdx.x;
    float* row = x + (size_t)s * DIM;
    float ss = 0.f;
    for (int c = tid; c < DIM; c += 256) { float v = row[c]; ss += v * v; }
    #pragma unroll
    for (int off = 32; off > 0; off >>= 1) ss += __shfl_down(ss, off, 64);
    __shared__ float red[4];
    if ((tid & 63) == 0) red[tid >> 6] = ss;
    __syncthreads();
    const float tot = red[0] + red[1] + red[2] + red[3];
    const float scale = rsqrtf(tot / (float)DIM + 1e-6f);
    const int f = *fp, h = *hp, ww = *wp, gi = *gip;
    const int hw = h * ww;
    const int fi = s / hw;
    const int rem = s - fi * hw;
    const int hi = rem / ww;
    const int wi = rem - hi * ww;
    const int sf = gi * f;
    for (int p = tid; p < DIM / 2; p += 256) {
        int n = p >> 6, i = p & 63;
        int pos = (i < 22) ? (sf + fi) : (i < 43) ? hi : wi;
        float cs = freqs[pos * 128 + i * 2];
        float sn = freqs[pos * 128 + i * 2 + 1];
        int base = n * HD + 2 * i;
        float x0 = row[base] * scale * w[base];
        float x1 = row[base + 1] * scale * w[base + 1];
        row[base] = x0 * cs - x1 * sn;
        row[base + 1] = x0 * sn + x1 * cs;
    }
}

// ---------------- K prep: fp16 hi/lo, MFMA-frag-linear tiles ----------------
__global__ __launch_bounds__(256) void khl_prep(
    const float* __restrict__ kws, const float* __restrict__ kcache,
    _Float16* __restrict__ Khg, _Float16* __restrict__ Klg,
    int S, int NT, const int* __restrict__ gip)
{
    const int t = blockIdx.x, n = blockIdx.y;
    const int tid = threadIdx.x;
    const int lane = tid & 63;
    const int l16 = lane & 15, quad = lane >> 4;
    const int start = gip[0] * S;
    const int nk = start + S;
    _Float16* outh = Khg + ((size_t)n * NT + t) * 4096;
    _Float16* outl = Klg + ((size_t)n * NT + t) * 4096;
    #pragma unroll
    for (int fi = 0; fi < 2; ++fi) {
        const int f = (tid >> 6) + fi * 4;
        const int ks = f >> 2, db = f & 3;
        const int j = t * KT + ks * 16 + l16;
        float4 a = make_float4(0,0,0,0), b = a;
        if (j < nk) {
            const float* src = (j < start) ? (kcache + (size_t)j * DIM)
                                           : (kws + (size_t)(j - start) * DIM);
            src += n * HD + db * 32 + quad * 8;
            a = *(const float4*)src;
            b = *(const float4*)(src + 4);
        }
        half8_t h, l; split8(a, b, h, l);
        *(half8_t*)&outh[(f * 64 + lane) * 8] = h;
        *(half8_t*)&outl[(f * 64 + lane) * 8] = l;
    }
}

// ---------------- V prep: fp16, transposed, frag-linear ----------------
__global__ __launch_bounds__(256) void vt_prep(
    const float* __restrict__ vws, const float* __restrict__ vcache,
    _Float16* __restrict__ Vtg, int S, int NT, const int* __restrict__ gip)
{
    const int t = blockIdx.x, n = blockIdx.y;
    const int tid = threadIdx.x;
    const int lane = tid & 63;
    const int l16 = lane & 15, quad = lane >> 4;
    const int start = gip[0] * S;
    const int nk = start + S;
    _Float16* out = Vtg + ((size_t)n * NT + t) * 4096;
    #pragma unroll
    for (int fi = 0; fi < 2; ++fi) {
        const int ds = (tid >> 6) + fi * 4;
        const int dim = n * HD + ds * 16 + l16;
        half8_t h;
        #pragma unroll
        for (int j = 0; j < 8; ++j) {
            const int key = t * KT + quad * 8 + j;
            float v = 0.f;
            if (key < nk)
                v = (key < start) ? vcache[(size_t)key * DIM + dim]
                                  : vws[(size_t)(key - start) * DIM + dim];
            h[j] = (_Float16)v;
        }
        *(half8_t*)&out[(ds * 64 + lane) * 8] = h;
    }
}

// ---------------- MFMA flash attention: 2 waves, 32 q-rows/wave ----------------
#define PSTRH 40
__global__ __launch_bounds__(128, 2) void attn_mfma(
    const float* __restrict__ q,
    const _Float16* __restrict__ Khg, const _Float16* __restrict__ Klg,
    const _Float16* __restrict__ Vtg,
    float* __restrict__ Op, float* __restrict__ Ml,
    int S, int NT, const int* __restrict__ gip)
{
    __shared__ __align__(16) _Float16 KhL[4096], KlL[4096], VtL[4096];
    __shared__ __align__(16) _Float16 Ph[2][2][16][PSTRH];

    const int n = blockIdx.x;
    const int q0 = blockIdx.y * 64;
    const int ksp = blockIdx.z;
    const int tid = threadIdx.x;
    const int wave = tid >> 6;
    const int lane = tid & 63;
    const int l16 = lane & 15;
    const int quad = lane >> 4;
    const int start = gip[0] * S;
    const int nk = start + S;
    const int totTiles = (nk + KT - 1) / KT;
    const int tilesPer = (totTiles + KSPLIT - 1) / KSPLIT;
    const int t0 = ksp * tilesPer;
    const int t1 = min(t0 + tilesPer, totTiles);
    const float sc = 0.08838834764831845f;

    // ---- Q fragments: 2 q-subtiles per wave ----
    half8_t qh[2][4], ql[2][4];
    #pragma unroll
    for (int qs = 0; qs < 2; ++qs) {
        const int qrow = q0 + wave * 32 + qs * 16 + l16;
        const bool qv = qrow < S;
        const float* qp = q + (size_t)(qv ? qrow : 0) * DIM + n * HD + quad * 8;
        #pragma unroll
        for (int db = 0; db < 4; ++db) {
            float4 a = make_float4(0,0,0,0), b = a;
            if (qv) { a = *(const float4*)(qp + db * 32); b = *(const float4*)(qp + db * 32 + 4); }
            split8(a, b, qh[qs][db], ql[qs][db]);
        }
    }

    half8_t ones_f;
    {
        _Float16 ov = (l16 == 0) ? (_Float16)1.0f : (_Float16)0.0f;
        #pragma unroll
        for (int j = 0; j < 8; ++j) ones_f[j] = ov;
    }

    f32x4 O[2][9];
    #pragma unroll
    for (int qs = 0; qs < 2; ++qs)
        #pragma unroll
        for (int ds = 0; ds < 9; ++ds) O[qs][ds] = (f32x4){0.f, 0.f, 0.f, 0.f};

    for (int t = t0; t < t1; ++t) {
        __syncthreads();
        // ---- async stage K/V tiles (frag-linear, conflict-free) ----
        {
            const _Float16* kb = Khg + ((size_t)n * NT + t) * 4096;
            const _Float16* lb = Klg + ((size_t)n * NT + t) * 4096;
            const _Float16* vb = Vtg + ((size_t)n * NT + t) * 4096;
            #pragma unroll
            for (int i = 0; i < 4; ++i) {
                const int chunk = i * 2 + wave;
                gl2lds16(kb + chunk * 512 + lane * 8, &KhL[chunk * 512]);
                gl2lds16(lb + chunk * 512 + lane * 8, &KlL[chunk * 512]);
                gl2lds16(vb + chunk * 512 + lane * 8, &VtL[chunk * 512]);
            }
        }
        __syncthreads();

        // ---- S = Q K^T (hh + hl + lh) ----
        f32x4 sacc[2][2];
        #pragma unroll
        for (int qs = 0; qs < 2; ++qs) { sacc[qs][0] = (f32x4){0.f,0.f,0.f,0.f}; sacc[qs][1] = (f32x4){0.f,0.f,0.f,0.f}; }
        #pragma unroll
        for (int ks = 0; ks < 2; ++ks) {
            #pragma unroll
            for (int db = 0; db < 4; ++db) {
                half8_t bh = ((const half8_t*)KhL)[(ks*4 + db)*64 + lane];
                half8_t bl = ((const half8_t*)KlL)[(ks*4 + db)*64 + lane];
                #pragma unroll
                for (int qs = 0; qs < 2; ++qs) {
                    sacc[qs][ks] = __builtin_amdgcn_mfma_f32_16x16x32_f16(qh[qs][db], bh, sacc[qs][ks], 0, 0, 0);
                    sacc[qs][ks] = __builtin_amdgcn_mfma_f32_16x16x32_f16(qh[qs][db], bl, sacc[qs][ks], 0, 0, 0);
                    sacc[qs][ks] = __builtin_amdgcn_mfma_f32_16x16x32_f16(ql[qs][db], bh, sacc[qs][ks], 0, 0, 0);
                }
            }
        }

        // ---- fixed-max softmax -> fp16 P in LDS ----
        const int k0 = t * KT;
        const bool v0 = (k0 + l16) < nk;
        const bool v1 = (k0 + 16 + l16) < nk;
        #pragma unroll
        for (int qs = 0; qs < 2; ++qs) {
            #pragma unroll
            for (int r = 0; r < 4; ++r) {
                float p0 = v0 ? __expf(sacc[qs][0][r] * sc - MFIX) : 0.f;
                float p1 = v1 ? __expf(sacc[qs][1][r] * sc - MFIX) : 0.f;
                Ph[wave][qs][quad * 4 + r][l16] = (_Float16)p0;
                Ph[wave][qs][quad * 4 + r][16 + l16] = (_Float16)p1;
            }
        }

        // ---- P -> A-layout (wave-private; lgkmcnt only, no barrier) ----
        half8_t ph[2];
        #pragma unroll
        for (int qs = 0; qs < 2; ++qs)
            ph[qs] = *(const half8_t*)&Ph[wave][qs][l16][quad * 8];

        // ---- O += P V (+ l via ones-frag) ----
        #pragma unroll
        for (int ds = 0; ds < 8; ++ds) {
            half8_t vh = ((const half8_t*)VtL)[ds*64 + lane];
            O[0][ds] = __builtin_amdgcn_mfma_f32_16x16x32_f16(ph[0], vh, O[0][ds], 0, 0, 0);
            O[1][ds] = __builtin_amdgcn_mfma_f32_16x16x32_f16(ph[1], vh, O[1][ds], 0, 0, 0);
        }
        O[0][8] = __builtin_amdgcn_mfma_f32_16x16x32_f16(ph[0], ones_f, O[0][8], 0, 0, 0);
        O[1][8] = __builtin_amdgcn_mfma_f32_16x16x32_f16(ph[1], ones_f, O[1][8], 0, 0, 0);
    }

    // ---- write partials ----
    #pragma unroll
    for (int qs = 0; qs < 2; ++qs)
        #pragma unroll
        for (int r = 0; r < 4; ++r) {
            const int row = q0 + wave * 32 + qs * 16 + quad * 4 + r;
            if (row < S) {
                float* op = Op + (((size_t)ksp * NH + n) * S + row) * HD + l16;
                #pragma unroll
                for (int ds = 0; ds < 8; ++ds) op[ds * 16] = O[qs][ds][r];
                if (l16 == 0)
                    Ml[((size_t)ksp * NH + n) * S + row] = O[qs][8][r];
            }
        }
}

// ---------------- merge split-K partials -> fp16 hi/lo o ----------------
__global__ __launch_bounds__(256) void attn_merge(
    const float* __restrict__ Op, const float* __restrict__ Ml,
    _Float16* __restrict__ oh, _Float16* __restrict__ ol, int S)
{
    const int idx = blockIdx.x * 256 + threadIdx.x;
    const int total = NH * S * HD / 2;
    if (idx >= total) return;
    const int d0 = (idx & 63) * 2;
    const int t = idx >> 6;
    const int row = t % S;
    const int n = t / S;
    float num0 = 0.f, num1 = 0.f, den = 0.f;
    #pragma unroll
    for (int ks = 0; ks < KSPLIT; ++ks) {
        const size_t base = ((size_t)ks * NH + n) * S + row;
        num0 += Op[base * HD + d0];
        num1 += Op[base * HD + d0 + 1];
        den += Ml[base];
    }
    const float v0 = num0 / den, v1 = num1 / den;
    half2_t h = pkrtz(v0, v1);
    half2_t l = pkrtz(v0 - (float)h.x, v1 - (float)h.y);
    const size_t oidx = (size_t)row * DIM + n * HD + d0;
    *(half2_t*)&oh[oidx] = h;
    *(half2_t*)&ol[oidx] = l;
}

extern "C" void kernel_launch(void* const* d_in, const int* in_sizes, int n_in,
                              void* d_out, int out_size, void* d_ws, size_t ws_size,
                              hipStream_t stream)
{
    const float* x      = (const float*)d_in[0];
    const float* wq     = (const float*)d_in[1];
    const float* bq     = (const float*)d_in[2];
    const float* wk     = (const float*)d_in[3];
    const float* bk     = (const float*)d_in[4];
    const float* wv     = (const float*)d_in[5];
    const float* bv     = (const float*)d_in[6];
    const float* wo     = (const float*)d_in[7];
    const float* bo     = (const float*)d_in[8];
    const float* nqw    = (const float*)d_in[9];
    const float* nkw    = (const float*)d_in[10];
    const float* freqs  = (const float*)d_in[11];
    const float* kcache = (const float*)d_in[12];
    const float* vcache = (const float*)d_in[13];
    const int*   fp     = (const int*)d_in[14];
    const int*   hp     = (const int*)d_in[15];
    const int*   wp     = (const int*)d_in[16];
    const int*   gip    = (const int*)d_in[17];

    const int S = in_sizes[0] / DIM;
    const int total = in_sizes[12] / (NH * HD);
    const int NT = (total + KT - 1) / KT;
    const size_t sd = (size_t)S * DIM;
    const size_t wsz = (size_t)DIM * DIM;

    char* p = (char*)d_ws;
    float* q  = (float*)p;            p += sd * 4;
    float* k  = (float*)p;            p += sd * 4;
    float* v  = (float*)p;            p += sd * 4;
    float* Op = (float*)p;            p += (size_t)KSPLIT * NH * S * HD * 4;
    float* Ml = (float*)p;            p += (size_t)KSPLIT * NH * S * 4;
    _Float16* Khg = (_Float16*)p;     p += (size_t)NH * NT * 4096 * 2;
    _Float16* Klg = (_Float16*)p;     p += (size_t)NH * NT * 4096 * 2;
    _Float16* Vtg = (_Float16*)p;     p += (size_t)NH * NT * 4096 * 2;
    _Float16* xh  = (_Float16*)p;     p += sd * 2;
    _Float16* xl  = (_Float16*)p;     p += sd * 2;
    _Float16* oh  = (_Float16*)p;     p += sd * 2;
    _Float16* ol  = (_Float16*)p;     p += sd * 2;
    _Float16* wqh = (_Float16*)p;     p += wsz * 2;
    _Float16* wql = (_Float16*)p;     p += wsz * 2;
    _Float16* wkh = (_Float16*)p;     p += wsz * 2;
    _Float16* wkl = (_Float16*)p;     p += wsz * 2;
    _Float16* wvh = (_Float16*)p;     p += wsz * 2;
    _Float16* wvl = (_Float16*)p;     p += wsz * 2;
    _Float16* woh = (_Float16*)p;     p += wsz * 2;
    _Float16* wol = (_Float16*)p;     p += wsz * 2;
    float* out = (float*)d_out;

    const int mt = (S + 127) / 128;
    const int xn8 = (int)(sd / 8), wn8 = (int)(wsz / 8);

    cvt_hl<<<dim3((xn8 + 255) / 256), dim3(256), 0, stream>>>(x, xh, xl, xn8);
    cvt_hl<<<dim3((wn8 + 255) / 256), dim3(256), 0, stream>>>(wq, wqh, wql, wn8);
    cvt_hl<<<dim3((wn8 + 255) / 256), dim3(256), 0, stream>>>(wk, wkh, wkl, wn8);
    cvt_hl<<<dim3((wn8 + 255) / 256), dim3(256), 0, stream>>>(wv, wvh, wvl, wn8);
    cvt_hl<<<dim3((wn8 + 255) / 256), dim3(256), 0, stream>>>(wo, woh, wol, wn8);

    gemm_f16_tn<<<dim3(36, mt), dim3(256), 0, stream>>>(
        xh, xl, wqh, wql, wkh, wkl, wvh, wvl, bq, bk, bv, q, k, v, S);
    rms_rope_kernel<<<dim3(S), dim3(256), 0, stream>>>(q, nqw, freqs, fp, hp, wp, gip);
    rms_rope_kernel<<<dim3(S), dim3(256), 0, stream>>>(k, nkw, freqs, fp, hp, wp, gip);
    khl_prep<<<dim3(NT, NH), dim3(256), 0, stream>>>(k, kcache, Khg, Klg, S, NT, gip);
    vt_prep<<<dim3(NT, NH), dim3(256), 0, stream>>>(v, vcache, Vtg, S, NT, gip);
    attn_mfma<<<dim3(NH, (S + 63) / 64, KSPLIT), dim3(128), 0, stream>>>(
        q, Khg, Klg, Vtg, Op, Ml, S, NT, gip);
    attn_merge<<<dim3((NH * S * HD / 2 + 255) / 256), dim3(256), 0, stream>>>(Op, Ml, oh, ol, S);
    gemm_f16_tn<<<dim3(12, mt), dim3(256), 0, stream>>>(
        oh, ol, woh, wol, woh, wol, woh, wol, bo, bo, bo, out, out, out, S);
}